// Round 9
// baseline (276.327 us; speedup 1.0000x reference)
//
#include <hip/hip_runtime.h>
#include <hip/hip_bf16.h>

#define NFREQ 512
#define KDIM  1024   // 2*NFREQ combined (magn || phase)
#define CDIM  1024   // NFFT output channels
#define TDIM  4096
#define BATCH 8
#define NT    16     // K-tiles of 64

typedef __bf16 bf16;
typedef __attribute__((ext_vector_type(8))) __bf16 bf16x8;
typedef __attribute__((ext_vector_type(4))) float f32x4;

__device__ __forceinline__ void gload_lds16(const bf16* g, void* l) {
    __builtin_amdgcn_global_load_lds(
        (const __attribute__((address_space(1))) void*)g,
        (__attribute__((address_space(3))) void*)l, 16, 0, 0);
}

// ---------------- transpose + prep (fused launch, z selects role) ----------------
// z==0/1: [b][f][t] f32 -> Xt[b][t][k] bf16 (k = z*NFREQ + f)
// z==2  : Kc[c][k] = RK[c][k]/1024 (k<512), -IK[c][k-512]/1024 (k>=512)
__global__ __launch_bounds__(256) void transpose_prep(const float* __restrict__ magn,
                                                      const float* __restrict__ phase,
                                                      const float* __restrict__ rk,
                                                      const float* __restrict__ ik,
                                                      bf16* __restrict__ Xt,
                                                      bf16* __restrict__ Kc) {
    const int tid = threadIdx.x;
    const int src = blockIdx.z;

    if (src == 2) {                      // prep: 8*512 = 4096 block-slots, exact
        int idx = (blockIdx.y * 512 + blockIdx.x) * 256 + tid;   // 0 .. 1M-1
        int c = idx >> 10;
        int k = idx & 1023;
        float v = (k < NFREQ) ? rk[c * NFREQ + k] : -ik[c * NFREQ + (k - NFREQ)];
        Kc[idx] = (bf16)(v * (1.0f / 1024.0f));
        return;
    }

    __shared__ bf16 tile[64][68];
    const int tt  = blockIdx.x & 63;
    const int ft  = blockIdx.x >> 6;
    const int b   = blockIdx.y;
    const float* in = src ? phase : magn;
    const int f0 = ft * 64, t0 = tt * 64;
    const size_t base = (size_t)b * NFREQ * TDIM;

    const int r0 = tid >> 4;
    const int c4 = (tid & 15) * 4;
#pragma unroll
    for (int i = 0; i < 4; i++) {
        int r = r0 + i * 16;
        const float4 v = *(const float4*)&in[base + (size_t)(f0 + r) * TDIM + t0 + c4];
        tile[r][c4 + 0] = (bf16)v.x;
        tile[r][c4 + 1] = (bf16)v.y;
        tile[r][c4 + 2] = (bf16)v.z;
        tile[r][c4 + 3] = (bf16)v.w;
    }
    __syncthreads();
    const int kbase = src * NFREQ + f0;
#pragma unroll
    for (int i = 0; i < 2; i++) {
        int ch = tid + 256 * i;
        int tr = ch >> 3;
        int c8 = (ch & 7) * 8;
        bf16x8 o;
#pragma unroll
        for (int j = 0; j < 8; j++) o[j] = tile[c8 + j][tr];
        *(bf16x8*)&Xt[((size_t)b * TDIM + t0 + tr) * KDIM + kbase + c8] = o;
    }
}

// ---------------- GEMM: 256x256 tile, BK=64, 8-phase counted-vmcnt ----------------
// out[b][c][t] = sum_k Kc[c][k] * Xt[b*TDIM+t][k]
// Persistent bn-pair: grid 32x8, x = bm*8+bnp; block does bn = bnp, bnp+8.
// XCD: gid%8 = x%8 = bnp -> the 4 bm-sharers of a (b,bn) panel share an XCD
// for BOTH tiles (R4-verified property). A-panel (bm) is L2-warm for tile 2;
// tile-1 C-store drain overlaps tile-2 prologue loads. K-loop is R4 verbatim.
__global__ __launch_bounds__(512, 2) void gemm8(const bf16* __restrict__ Kc,
                                                const bf16* __restrict__ Xt,
                                                float* __restrict__ out) {
    extern __shared__ __align__(16) char smem[];   // 128 KB: [buf][A 32K | B 32K]

    const int tid = threadIdx.x;
    const int w = tid >> 6;          // wave 0..7
    const int l = tid & 63;

    const int x   = blockIdx.x;      // 0..31
    const int bm  = x >> 3;          // 0..3  (c tiles of 256)
    const int bnp = x & 7;           // 0..7
    const int b   = blockIdx.y;

    const bf16* Ab = Kc + (size_t)(bm * 256) * KDIM;

    // staging geometry (R4 verbatim)
    const int srow = ((w >> 2) * 128) + ((w & 3) * 8);
    const int ssub = l >> 3;                    // 0..7 row within wave chunk
    const int scol = ((l & 7) ^ ssub) * 8;      // inverse-swizzled source col

    // fragment-read geometry (R4 verbatim)
    const int wr = w >> 2;           // 0..1 (M)
    const int wc = w & 3;            // 0..3 (N)
    const int fr = l & 15;
    const int l16 = l >> 4;          // 0..3
    const int fx = fr & 7;

#define STAGE_A(curb, q, kt) \
    gload_lds16(Ab + (size_t)(srow + (q)*32 + ssub) * KDIM + (kt)*64 + scol, \
                smem + (curb)*65536 + (srow + (q)*32) * 128)
#define STAGE_B(curb, q, kt) \
    gload_lds16(Bbase + (size_t)(srow + (q)*32 + ssub) * KDIM + (kt)*64 + scol, \
                smem + (curb)*65536 + 32768 + (srow + (q)*32) * 128)

    for (int ti = 0; ti < 2; ++ti) {
        const int bn = bnp + ti * 8;
        const bf16* Bbase = Xt + ((size_t)b * TDIM + bn * 256) * KDIM;

        f32x4 acc[8][4] = {};

        // prologue: tile0 fully into buf0; tile1 A-q0..2 into buf1 (R4 verbatim)
#pragma unroll
        for (int q = 0; q < 4; q++) STAGE_A(0, q, 0);
#pragma unroll
        for (int q = 0; q < 4; q++) STAGE_B(0, q, 0);
        STAGE_A(1, 0, 1); STAGE_A(1, 1, 1); STAGE_A(1, 2, 1);
        asm volatile("s_waitcnt vmcnt(3)" ::: "memory");
        __builtin_amdgcn_s_barrier();
        __builtin_amdgcn_sched_barrier(0);

        for (int v = 0; v < NT; ++v) {
            const int cur = v & 1;
            const char* At = smem + cur * 65536;
            const char* Bt = At + 32768;
            bf16x8 bfr[4][2];

#pragma unroll
            for (int p = 0; p < 4; p++) {
                bf16x8 afr[2][2];
#pragma unroll
                for (int mi = 0; mi < 2; mi++)
#pragma unroll
                    for (int kk = 0; kk < 2; kk++) {
                        const int r = wr * 128 + (p * 2 + mi) * 16 + fr;
                        const int off = r * 128 + (((kk * 4 + l16) ^ fx) * 16);
                        afr[mi][kk] = *(const bf16x8*)(At + off);
                    }
                if (p == 0) {
#pragma unroll
                    for (int n = 0; n < 4; n++)
#pragma unroll
                        for (int kk = 0; kk < 2; kk++) {
                            const int r = wc * 64 + n * 16 + fr;
                            const int off = r * 128 + (((kk * 4 + l16) ^ fx) * 16);
                            bfr[n][kk] = *(const bf16x8*)(Bt + off);
                        }
                }

                // stage issues (regions dead since previous closing barrier)
                if (p == 0) {
                    if (v + 1 < NT) {
                        const int nc = cur ^ 1;
                        STAGE_A(nc, 3, v + 1);
                        STAGE_B(nc, 0, v + 1); STAGE_B(nc, 1, v + 1);
                        STAGE_B(nc, 2, v + 1); STAGE_B(nc, 3, v + 1);
                    }
                } else {
                    if (v + 2 < NT) STAGE_A(cur, p - 1, v + 2);
                }

                __builtin_amdgcn_s_barrier();
                __builtin_amdgcn_s_setprio(1);
#pragma unroll
                for (int mi = 0; mi < 2; mi++)
#pragma unroll
                    for (int n = 0; n < 4; n++)
#pragma unroll
                        for (int kk = 0; kk < 2; kk++)
                            acc[p * 2 + mi][n] = __builtin_amdgcn_mfma_f32_16x16x32_bf16(
                                afr[mi][kk], bfr[n][kk], acc[p * 2 + mi][n], 0, 0, 0);
                __builtin_amdgcn_s_setprio(0);
                if (p == 3) {
                    if (v < NT - 2) { asm volatile("s_waitcnt vmcnt(3)" ::: "memory"); }
                    else            { asm volatile("s_waitcnt vmcnt(0)" ::: "memory"); }
                }
                __builtin_amdgcn_s_barrier();
                __builtin_amdgcn_sched_barrier(0);
            }
        }

        // epilogue: C/D layout col = lane&15, row = (lane>>4)*4 + j (R4 verbatim)
        {
            const int cr = l16 * 4;
            const int cc = fr;
            float* obase = out + ((size_t)b * CDIM + bm * 256 + wr * 128) * TDIM
                               + bn * 256 + wc * 64;
#pragma unroll
            for (int m = 0; m < 8; m++)
#pragma unroll
                for (int n = 0; n < 4; n++)
#pragma unroll
                    for (int j = 0; j < 4; j++)
                        obase[(size_t)(m * 16 + cr + j) * TDIM + n * 16 + cc] = acc[m][n][j];
        }
        // next ti's prologue gload_lds writes happen only after this wave passed
        // the v=NT-1 closing barrier, which ordered all waves' last LDS reads.
    }
#undef STAGE_A
#undef STAGE_B
}

// ---------------- fallback (ws too small): naive f32 ----------------
__global__ __launch_bounds__(256) void naive_kernel(const float* __restrict__ m,
                                                    const float* __restrict__ p,
                                                    const float* __restrict__ rk,
                                                    const float* __restrict__ ik,
                                                    float* __restrict__ out) {
    size_t idx = (size_t)blockIdx.x * 256 + threadIdx.x;
    int t = idx & 4095;
    size_t r = idx >> 12;
    int c = (int)(r & 1023);
    int b = (int)(r >> 10);
    float acc = 0.f;
    for (int f = 0; f < NFREQ; f++) {
        acc += rk[c * NFREQ + f] * m[((size_t)b * NFREQ + f) * TDIM + t]
             - ik[c * NFREQ + f] * p[((size_t)b * NFREQ + f) * TDIM + t];
    }
    out[idx] = acc * (1.0f / 1024.0f);
}

extern "C" void kernel_launch(void* const* d_in, const int* in_sizes, int n_in,
                              void* d_out, int out_size, void* d_ws, size_t ws_size,
                              hipStream_t stream) {
    const float* magn  = (const float*)d_in[0];
    const float* phase = (const float*)d_in[1];
    const float* rk    = (const float*)d_in[2];
    const float* ik    = (const float*)d_in[3];
    float* out = (float*)d_out;

    const size_t kc_bytes = (size_t)CDIM * KDIM * sizeof(bf16);          // 2 MB
    const size_t xt_bytes = (size_t)BATCH * TDIM * KDIM * sizeof(bf16);  // 64 MB
    if (ws_size < kc_bytes + xt_bytes) {
        naive_kernel<<<(CDIM * TDIM * BATCH) / 256, 256, 0, stream>>>(magn, phase, rk, ik, out);
        return;
    }

    bf16* Kc = (bf16*)d_ws;
    bf16* Xt = (bf16*)((char*)d_ws + kc_bytes);

    (void)hipFuncSetAttribute((const void*)gemm8,
                              hipFuncAttributeMaxDynamicSharedMemorySize, 131072);

    transpose_prep<<<dim3(512, BATCH, 3), 256, 0, stream>>>(magn, phase, rk, ik, Xt, Kc);
    gemm8<<<dim3(32, BATCH), 512, 131072, stream>>>(Kc, Xt, out);
}

// Round 10
// 117.614 us; speedup vs baseline: 2.3494x; 2.3494x over previous
//
#include <hip/hip_runtime.h>
#include <hip/hip_bf16.h>

#define NFREQ 512
#define KDIM  1024   // 2*NFREQ combined (magn || phase)
#define CDIM  1024   // NFFT output channels
#define TDIM  4096
#define BATCH 8
#define NT    16     // K-tiles of 64

typedef __bf16 bf16;
typedef __attribute__((ext_vector_type(8))) __bf16 bf16x8;
typedef __attribute__((ext_vector_type(4))) float f32x4;

__device__ __forceinline__ void gload_lds16(const bf16* g, void* l) {
    __builtin_amdgcn_global_load_lds(
        (const __attribute__((address_space(1))) void*)g,
        (__attribute__((address_space(3))) void*)l, 16, 0, 0);
}

// ---------------- transpose + prep (fused launch, z selects role) ----------------
// z==0/1: [b][f][t] f32 -> Xt[b][t][k] bf16 (k = z*NFREQ + f)
// z==2  : Kc[c][k] = RK[c][k]/1024 (k<512), -IK[c][k-512]/1024 (k>=512)
__global__ __launch_bounds__(256) void transpose_prep(const float* __restrict__ magn,
                                                      const float* __restrict__ phase,
                                                      const float* __restrict__ rk,
                                                      const float* __restrict__ ik,
                                                      bf16* __restrict__ Xt,
                                                      bf16* __restrict__ Kc) {
    const int tid = threadIdx.x;
    const int src = blockIdx.z;

    if (src == 2) {                      // prep: 8*512 = 4096 block-slots, exact
        int idx = (blockIdx.y * 512 + blockIdx.x) * 256 + tid;   // 0 .. 1M-1
        int c = idx >> 10;
        int k = idx & 1023;
        float v = (k < NFREQ) ? rk[c * NFREQ + k] : -ik[c * NFREQ + (k - NFREQ)];
        Kc[idx] = (bf16)(v * (1.0f / 1024.0f));
        return;
    }

    __shared__ bf16 tile[64][68];
    const int tt  = blockIdx.x & 63;
    const int ft  = blockIdx.x >> 6;
    const int b   = blockIdx.y;
    const float* in = src ? phase : magn;
    const int f0 = ft * 64, t0 = tt * 64;
    const size_t base = (size_t)b * NFREQ * TDIM;

    const int r0 = tid >> 4;
    const int c4 = (tid & 15) * 4;
#pragma unroll
    for (int i = 0; i < 4; i++) {
        int r = r0 + i * 16;
        const float4 v = *(const float4*)&in[base + (size_t)(f0 + r) * TDIM + t0 + c4];
        tile[r][c4 + 0] = (bf16)v.x;
        tile[r][c4 + 1] = (bf16)v.y;
        tile[r][c4 + 2] = (bf16)v.z;
        tile[r][c4 + 3] = (bf16)v.w;
    }
    __syncthreads();
    const int kbase = src * NFREQ + f0;
#pragma unroll
    for (int i = 0; i < 2; i++) {
        int ch = tid + 256 * i;
        int tr = ch >> 3;
        int c8 = (ch & 7) * 8;
        bf16x8 o;
#pragma unroll
        for (int j = 0; j < 8; j++) o[j] = tile[c8 + j][tr];
        *(bf16x8*)&Xt[((size_t)b * TDIM + t0 + tr) * KDIM + kbase + c8] = o;
    }
}

// ---------------- GEMM: 256x256 tile, BK=64, 8-phase counted-vmcnt ----------------
// out[b][c][t] = sum_k Kc[c][k] * Xt[b*TDIM+t][k]
// R4 verbatim. One tile per WG (persistence is BANNED: R3/R9 both showed
// multi-tile WG loops desynchronize B-panel sharers -> L2 reuse collapse,
// FETCH ~230 MB + WRITE ~285 MB, 3x slowdown).
// Decode: bm = x>>4, bn = x&15, b = y. gid%8 = x%8 -> the 4 bm-sharers of a
// (b,bn) B-panel land on one XCD, lockstep K -> B fetched once, 3x L2 hits.
__global__ __launch_bounds__(512, 2) void gemm8(const bf16* __restrict__ Kc,
                                                const bf16* __restrict__ Xt,
                                                float* __restrict__ out) {
    extern __shared__ __align__(16) char smem[];   // 128 KB: [buf][A 32K | B 32K]

    const int tid = threadIdx.x;
    const int w = tid >> 6;          // wave 0..7
    const int l = tid & 63;

    const int x  = blockIdx.x;
    const int bm = x >> 4;           // 0..3  (c tiles of 256)
    const int bn = x & 15;           // 0..15 (t tiles of 256)
    const int b  = blockIdx.y;

    const bf16* Ab    = Kc + (size_t)(bm * 256) * KDIM;
    const bf16* Bbase = Xt + ((size_t)b * TDIM + bn * 256) * KDIM;

    // staging geometry
    const int srow = ((w >> 2) * 128) + ((w & 3) * 8);
    const int ssub = l >> 3;                    // 0..7 row within wave chunk
    const int scol = ((l & 7) ^ ssub) * 8;      // inverse-swizzled source col

    // fragment-read geometry
    const int wr = w >> 2;           // 0..1 (M)
    const int wc = w & 3;            // 0..3 (N)
    const int fr = l & 15;
    const int l16 = l >> 4;          // 0..3
    const int fx = fr & 7;

    f32x4 acc[8][4] = {};

#define STAGE_A(curb, q, kt) \
    gload_lds16(Ab + (size_t)(srow + (q)*32 + ssub) * KDIM + (kt)*64 + scol, \
                smem + (curb)*65536 + (srow + (q)*32) * 128)
#define STAGE_B(curb, q, kt) \
    gload_lds16(Bbase + (size_t)(srow + (q)*32 + ssub) * KDIM + (kt)*64 + scol, \
                smem + (curb)*65536 + 32768 + (srow + (q)*32) * 128)

    // prologue: tile0 fully into buf0; tile1 A-q0..2 into buf1
#pragma unroll
    for (int q = 0; q < 4; q++) STAGE_A(0, q, 0);
#pragma unroll
    for (int q = 0; q < 4; q++) STAGE_B(0, q, 0);
    STAGE_A(1, 0, 1); STAGE_A(1, 1, 1); STAGE_A(1, 2, 1);
    asm volatile("s_waitcnt vmcnt(3)" ::: "memory");
    __builtin_amdgcn_s_barrier();
    __builtin_amdgcn_sched_barrier(0);

    for (int v = 0; v < NT; ++v) {
        const int cur = v & 1;
        const char* At = smem + cur * 65536;
        const char* Bt = At + 32768;
        bf16x8 bfr[4][2];

#pragma unroll
        for (int p = 0; p < 4; p++) {
            bf16x8 afr[2][2];
#pragma unroll
            for (int mi = 0; mi < 2; mi++)
#pragma unroll
                for (int kk = 0; kk < 2; kk++) {
                    const int r = wr * 128 + (p * 2 + mi) * 16 + fr;
                    const int off = r * 128 + (((kk * 4 + l16) ^ fx) * 16);
                    afr[mi][kk] = *(const bf16x8*)(At + off);
                }
            if (p == 0) {
#pragma unroll
                for (int n = 0; n < 4; n++)
#pragma unroll
                    for (int kk = 0; kk < 2; kk++) {
                        const int r = wc * 64 + n * 16 + fr;
                        const int off = r * 128 + (((kk * 4 + l16) ^ fx) * 16);
                        bfr[n][kk] = *(const bf16x8*)(Bt + off);
                    }
            }

            // stage issues (regions dead since previous closing barrier)
            if (p == 0) {
                if (v + 1 < NT) {
                    const int nc = cur ^ 1;
                    STAGE_A(nc, 3, v + 1);
                    STAGE_B(nc, 0, v + 1); STAGE_B(nc, 1, v + 1);
                    STAGE_B(nc, 2, v + 1); STAGE_B(nc, 3, v + 1);
                }
            } else {
                if (v + 2 < NT) STAGE_A(cur, p - 1, v + 2);
            }

            __builtin_amdgcn_s_barrier();
            __builtin_amdgcn_s_setprio(1);
#pragma unroll
            for (int mi = 0; mi < 2; mi++)
#pragma unroll
                for (int n = 0; n < 4; n++)
#pragma unroll
                    for (int kk = 0; kk < 2; kk++)
                        acc[p * 2 + mi][n] = __builtin_amdgcn_mfma_f32_16x16x32_bf16(
                            afr[mi][kk], bfr[n][kk], acc[p * 2 + mi][n], 0, 0, 0);
            __builtin_amdgcn_s_setprio(0);
            if (p == 3) {
                if (v < NT - 2) { asm volatile("s_waitcnt vmcnt(3)" ::: "memory"); }
                else            { asm volatile("s_waitcnt vmcnt(0)" ::: "memory"); }
            }
            __builtin_amdgcn_s_barrier();
            __builtin_amdgcn_sched_barrier(0);
        }
    }
#undef STAGE_A
#undef STAGE_B

    // epilogue: C/D layout col = lane&15, row = (lane>>4)*4 + j
    const int cr = l16 * 4;
    const int cc = fr;
    float* obase = out + ((size_t)b * CDIM + bm * 256 + wr * 128) * TDIM + bn * 256 + wc * 64;
#pragma unroll
    for (int m = 0; m < 8; m++)
#pragma unroll
        for (int n = 0; n < 4; n++)
#pragma unroll
            for (int j = 0; j < 4; j++)
                obase[(size_t)(m * 16 + cr + j) * TDIM + n * 16 + cc] = acc[m][n][j];
}

// ---------------- fallback (ws too small): naive f32 ----------------
__global__ __launch_bounds__(256) void naive_kernel(const float* __restrict__ m,
                                                    const float* __restrict__ p,
                                                    const float* __restrict__ rk,
                                                    const float* __restrict__ ik,
                                                    float* __restrict__ out) {
    size_t idx = (size_t)blockIdx.x * 256 + threadIdx.x;
    int t = idx & 4095;
    size_t r = idx >> 12;
    int c = (int)(r & 1023);
    int b = (int)(r >> 10);
    float acc = 0.f;
    for (int f = 0; f < NFREQ; f++) {
        acc += rk[c * NFREQ + f] * m[((size_t)b * NFREQ + f) * TDIM + t]
             - ik[c * NFREQ + f] * p[((size_t)b * NFREQ + f) * TDIM + t];
    }
    out[idx] = acc * (1.0f / 1024.0f);
}

extern "C" void kernel_launch(void* const* d_in, const int* in_sizes, int n_in,
                              void* d_out, int out_size, void* d_ws, size_t ws_size,
                              hipStream_t stream) {
    const float* magn  = (const float*)d_in[0];
    const float* phase = (const float*)d_in[1];
    const float* rk    = (const float*)d_in[2];
    const float* ik    = (const float*)d_in[3];
    float* out = (float*)d_out;

    const size_t kc_bytes = (size_t)CDIM * KDIM * sizeof(bf16);          // 2 MB
    const size_t xt_bytes = (size_t)BATCH * TDIM * KDIM * sizeof(bf16);  // 64 MB
    if (ws_size < kc_bytes + xt_bytes) {
        naive_kernel<<<(CDIM * TDIM * BATCH) / 256, 256, 0, stream>>>(magn, phase, rk, ik, out);
        return;
    }

    bf16* Kc = (bf16*)d_ws;
    bf16* Xt = (bf16*)((char*)d_ws + kc_bytes);

    (void)hipFuncSetAttribute((const void*)gemm8,
                              hipFuncAttributeMaxDynamicSharedMemorySize, 131072);

    transpose_prep<<<dim3(512, BATCH, 3), 256, 0, stream>>>(magn, phase, rk, ik, Xt, Kc);
    gemm8<<<dim3(64, BATCH), 512, 131072, stream>>>(Kc, Xt, out);
}

// Round 11
// 116.403 us; speedup vs baseline: 2.3739x; 1.0104x over previous
//
#include <hip/hip_runtime.h>
#include <hip/hip_bf16.h>

#define NFREQ 512
#define KDIM  1024   // 2*NFREQ combined (magn || phase)
#define CDIM  1024   // NFFT output channels
#define TDIM  4096
#define BATCH 8
#define NT    16     // K-tiles of 64

typedef __bf16 bf16;
typedef __attribute__((ext_vector_type(8))) __bf16 bf16x8;
typedef __attribute__((ext_vector_type(4))) float f32x4;

__device__ __forceinline__ void gload_lds16(const bf16* g, void* l) {
    __builtin_amdgcn_global_load_lds(
        (const __attribute__((address_space(1))) void*)g,
        (__attribute__((address_space(3))) void*)l, 16, 0, 0);
}

// ---------------- transpose + prep (fused launch, z selects role) ----------------
// z==0/1: [b][f][t] f32 -> Xt[b][t][k] bf16 (k = z*NFREQ + f)
// z==2  : Kc[c][k] = RK[c][k]/1024 (k<512), -IK[c][k-512]/1024 (k>=512)
__global__ __launch_bounds__(256) void transpose_prep(const float* __restrict__ magn,
                                                      const float* __restrict__ phase,
                                                      const float* __restrict__ rk,
                                                      const float* __restrict__ ik,
                                                      bf16* __restrict__ Xt,
                                                      bf16* __restrict__ Kc) {
    const int tid = threadIdx.x;
    const int src = blockIdx.z;

    if (src == 2) {                      // prep: 8*512 = 4096 block-slots, exact
        int idx = (blockIdx.y * 512 + blockIdx.x) * 256 + tid;   // 0 .. 1M-1
        int c = idx >> 10;
        int k = idx & 1023;
        float v = (k < NFREQ) ? rk[c * NFREQ + k] : -ik[c * NFREQ + (k - NFREQ)];
        Kc[idx] = (bf16)(v * (1.0f / 1024.0f));
        return;
    }

    __shared__ bf16 tile[64][68];
    const int tt  = blockIdx.x & 63;
    const int ft  = blockIdx.x >> 6;
    const int b   = blockIdx.y;
    const float* in = src ? phase : magn;
    const int f0 = ft * 64, t0 = tt * 64;
    const size_t base = (size_t)b * NFREQ * TDIM;

    const int r0 = tid >> 4;
    const int c4 = (tid & 15) * 4;
#pragma unroll
    for (int i = 0; i < 4; i++) {
        int r = r0 + i * 16;
        const float4 v = *(const float4*)&in[base + (size_t)(f0 + r) * TDIM + t0 + c4];
        tile[r][c4 + 0] = (bf16)v.x;
        tile[r][c4 + 1] = (bf16)v.y;
        tile[r][c4 + 2] = (bf16)v.z;
        tile[r][c4 + 3] = (bf16)v.w;
    }
    __syncthreads();
    const int kbase = src * NFREQ + f0;
#pragma unroll
    for (int i = 0; i < 2; i++) {
        int ch = tid + 256 * i;
        int tr = ch >> 3;
        int c8 = (ch & 7) * 8;
        bf16x8 o;
#pragma unroll
        for (int j = 0; j < 8; j++) o[j] = tile[c8 + j][tr];
        *(bf16x8*)&Xt[((size_t)b * TDIM + t0 + tr) * KDIM + kbase + c8] = o;
    }
}

// ---------------- GEMM: 256x256 tile, BK=64, 8-phase counted-vmcnt ----------------
// out[b][c][t] = sum_k Kc[c][k] * Xt[b*TDIM+t][k]
// R4/R10 verbatim K-loop for v=0..NT-2. Tile NT-1 is PEELED: it stages
// nothing and no wave writes LDS, so it runs barrier-free; after phase p's
// MFMA the two now-final acc quarters (m=2p,2p+1) store immediately, so the
// C-write drains under the remaining phases' ds_read+MFMA (fused epilogue).
// One tile per WG (persistence BANNED: R3/R9 showed multi-tile WG loops
// desync B-panel sharers -> L2 collapse). Decode: bm=x>>4, bn=x&15, b=y;
// gid%8=x%8 -> 4 bm-sharers of a (b,bn) panel share an XCD, lockstep K.
__global__ __launch_bounds__(512, 2) void gemm8(const bf16* __restrict__ Kc,
                                                const bf16* __restrict__ Xt,
                                                float* __restrict__ out) {
    extern __shared__ __align__(16) char smem[];   // 128 KB: [buf][A 32K | B 32K]

    const int tid = threadIdx.x;
    const int w = tid >> 6;          // wave 0..7
    const int l = tid & 63;

    const int x  = blockIdx.x;
    const int bm = x >> 4;           // 0..3  (c tiles of 256)
    const int bn = x & 15;           // 0..15 (t tiles of 256)
    const int b  = blockIdx.y;

    const bf16* Ab    = Kc + (size_t)(bm * 256) * KDIM;
    const bf16* Bbase = Xt + ((size_t)b * TDIM + bn * 256) * KDIM;

    // staging geometry
    const int srow = ((w >> 2) * 128) + ((w & 3) * 8);
    const int ssub = l >> 3;                    // 0..7 row within wave chunk
    const int scol = ((l & 7) ^ ssub) * 8;      // inverse-swizzled source col

    // fragment-read geometry
    const int wr = w >> 2;           // 0..1 (M)
    const int wc = w & 3;            // 0..3 (N)
    const int fr = l & 15;
    const int l16 = l >> 4;          // 0..3
    const int fx = fr & 7;

    f32x4 acc[8][4] = {};

#define STAGE_A(curb, q, kt) \
    gload_lds16(Ab + (size_t)(srow + (q)*32 + ssub) * KDIM + (kt)*64 + scol, \
                smem + (curb)*65536 + (srow + (q)*32) * 128)
#define STAGE_B(curb, q, kt) \
    gload_lds16(Bbase + (size_t)(srow + (q)*32 + ssub) * KDIM + (kt)*64 + scol, \
                smem + (curb)*65536 + 32768 + (srow + (q)*32) * 128)

    // prologue: tile0 fully into buf0; tile1 A-q0..2 into buf1
#pragma unroll
    for (int q = 0; q < 4; q++) STAGE_A(0, q, 0);
#pragma unroll
    for (int q = 0; q < 4; q++) STAGE_B(0, q, 0);
    STAGE_A(1, 0, 1); STAGE_A(1, 1, 1); STAGE_A(1, 2, 1);
    asm volatile("s_waitcnt vmcnt(3)" ::: "memory");
    __builtin_amdgcn_s_barrier();
    __builtin_amdgcn_sched_barrier(0);

    for (int v = 0; v < NT - 1; ++v) {
        const int cur = v & 1;
        const char* At = smem + cur * 65536;
        const char* Bt = At + 32768;
        bf16x8 bfr[4][2];

#pragma unroll
        for (int p = 0; p < 4; p++) {
            bf16x8 afr[2][2];
#pragma unroll
            for (int mi = 0; mi < 2; mi++)
#pragma unroll
                for (int kk = 0; kk < 2; kk++) {
                    const int r = wr * 128 + (p * 2 + mi) * 16 + fr;
                    const int off = r * 128 + (((kk * 4 + l16) ^ fx) * 16);
                    afr[mi][kk] = *(const bf16x8*)(At + off);
                }
            if (p == 0) {
#pragma unroll
                for (int n = 0; n < 4; n++)
#pragma unroll
                    for (int kk = 0; kk < 2; kk++) {
                        const int r = wc * 64 + n * 16 + fr;
                        const int off = r * 128 + (((kk * 4 + l16) ^ fx) * 16);
                        bfr[n][kk] = *(const bf16x8*)(Bt + off);
                    }
            }

            // stage issues (regions dead since previous closing barrier)
            if (p == 0) {
                if (v + 1 < NT) {
                    const int nc = cur ^ 1;
                    STAGE_A(nc, 3, v + 1);
                    STAGE_B(nc, 0, v + 1); STAGE_B(nc, 1, v + 1);
                    STAGE_B(nc, 2, v + 1); STAGE_B(nc, 3, v + 1);
                }
            } else {
                if (v + 2 < NT) STAGE_A(cur, p - 1, v + 2);
            }

            __builtin_amdgcn_s_barrier();
            __builtin_amdgcn_s_setprio(1);
#pragma unroll
            for (int mi = 0; mi < 2; mi++)
#pragma unroll
                for (int n = 0; n < 4; n++)
#pragma unroll
                    for (int kk = 0; kk < 2; kk++)
                        acc[p * 2 + mi][n] = __builtin_amdgcn_mfma_f32_16x16x32_bf16(
                            afr[mi][kk], bfr[n][kk], acc[p * 2 + mi][n], 0, 0, 0);
            __builtin_amdgcn_s_setprio(0);
            if (p == 3) {
                if (v < NT - 2) { asm volatile("s_waitcnt vmcnt(3)" ::: "memory"); }
                else            { asm volatile("s_waitcnt vmcnt(0)" ::: "memory"); }
            }
            __builtin_amdgcn_s_barrier();
            __builtin_amdgcn_sched_barrier(0);
        }
    }

    // -------- peeled final tile (v = NT-1, buf 1): barrier-free, fused C-write --
    {
        const char* At = smem + 65536;   // (NT-1)&1 == 1
        const char* Bt = At + 32768;
        const int cr = l16 * 4;
        const int cc = fr;
        float* obase = out + ((size_t)b * CDIM + bm * 256 + wr * 128) * TDIM
                           + bn * 256 + wc * 64;
        bf16x8 bfr[4][2];

#pragma unroll
        for (int p = 0; p < 4; p++) {
            bf16x8 afr[2][2];
#pragma unroll
            for (int mi = 0; mi < 2; mi++)
#pragma unroll
                for (int kk = 0; kk < 2; kk++) {
                    const int r = wr * 128 + (p * 2 + mi) * 16 + fr;
                    const int off = r * 128 + (((kk * 4 + l16) ^ fx) * 16);
                    afr[mi][kk] = *(const bf16x8*)(At + off);
                }
            if (p == 0) {
#pragma unroll
                for (int n = 0; n < 4; n++)
#pragma unroll
                    for (int kk = 0; kk < 2; kk++) {
                        const int r = wc * 64 + n * 16 + fr;
                        const int off = r * 128 + (((kk * 4 + l16) ^ fx) * 16);
                        bfr[n][kk] = *(const bf16x8*)(Bt + off);
                    }
            }

            __builtin_amdgcn_s_setprio(1);
#pragma unroll
            for (int mi = 0; mi < 2; mi++)
#pragma unroll
                for (int n = 0; n < 4; n++)
#pragma unroll
                    for (int kk = 0; kk < 2; kk++)
                        acc[p * 2 + mi][n] = __builtin_amdgcn_mfma_f32_16x16x32_bf16(
                            afr[mi][kk], bfr[n][kk], acc[p * 2 + mi][n], 0, 0, 0);
            __builtin_amdgcn_s_setprio(0);

            // quarters m = 2p, 2p+1 are now final -> store; drains under p+1
#pragma unroll
            for (int mi = 0; mi < 2; mi++) {
                const int m = p * 2 + mi;
#pragma unroll
                for (int n = 0; n < 4; n++)
#pragma unroll
                    for (int j = 0; j < 4; j++)
                        obase[(size_t)(m * 16 + cr + j) * TDIM + n * 16 + cc] = acc[m][n][j];
            }
        }
    }
#undef STAGE_A
#undef STAGE_B
}

// ---------------- fallback (ws too small): naive f32 ----------------
__global__ __launch_bounds__(256) void naive_kernel(const float* __restrict__ m,
                                                    const float* __restrict__ p,
                                                    const float* __restrict__ rk,
                                                    const float* __restrict__ ik,
                                                    float* __restrict__ out) {
    size_t idx = (size_t)blockIdx.x * 256 + threadIdx.x;
    int t = idx & 4095;
    size_t r = idx >> 12;
    int c = (int)(r & 1023);
    int b = (int)(r >> 10);
    float acc = 0.f;
    for (int f = 0; f < NFREQ; f++) {
        acc += rk[c * NFREQ + f] * m[((size_t)b * NFREQ + f) * TDIM + t]
             - ik[c * NFREQ + f] * p[((size_t)b * NFREQ + f) * TDIM + t];
    }
    out[idx] = acc * (1.0f / 1024.0f);
}

extern "C" void kernel_launch(void* const* d_in, const int* in_sizes, int n_in,
                              void* d_out, int out_size, void* d_ws, size_t ws_size,
                              hipStream_t stream) {
    const float* magn  = (const float*)d_in[0];
    const float* phase = (const float*)d_in[1];
    const float* rk    = (const float*)d_in[2];
    const float* ik    = (const float*)d_in[3];
    float* out = (float*)d_out;

    const size_t kc_bytes = (size_t)CDIM * KDIM * sizeof(bf16);          // 2 MB
    const size_t xt_bytes = (size_t)BATCH * TDIM * KDIM * sizeof(bf16);  // 64 MB
    if (ws_size < kc_bytes + xt_bytes) {
        naive_kernel<<<(CDIM * TDIM * BATCH) / 256, 256, 0, stream>>>(magn, phase, rk, ik, out);
        return;
    }

    bf16* Kc = (bf16*)d_ws;
    bf16* Xt = (bf16*)((char*)d_ws + kc_bytes);

    (void)hipFuncSetAttribute((const void*)gemm8,
                              hipFuncAttributeMaxDynamicSharedMemorySize, 131072);

    transpose_prep<<<dim3(512, BATCH, 3), 256, 0, stream>>>(magn, phase, rk, ik, Xt, Kc);
    gemm8<<<dim3(64, BATCH), 512, 131072, stream>>>(Kc, Xt, out);
}

// Round 12
// 104.325 us; speedup vs baseline: 2.6487x; 1.1158x over previous
//
#include <hip/hip_runtime.h>
#include <hip/hip_bf16.h>

#define NFREQ 512
#define KDIM  1024   // combined k (m || p)
#define CDIM  1024   // NFFT output channels
#define TDIM  4096
#define BATCH 8
#define NT    16     // K-tiles of 64

// LDS: per buffer A 256x64 bf16 = 32 KB, B 128x64 bf16 = 16 KB
#define ABYTES 32768
#define BUFSZ  49152
#define LDS_TOTAL 98304

typedef __bf16 bf16;
typedef __attribute__((ext_vector_type(8))) __bf16 bf16x8;
typedef __attribute__((ext_vector_type(4))) float f32x4;

__device__ __forceinline__ void gload_lds16(const bf16* g, void* l) {
    __builtin_amdgcn_global_load_lds(
        (const __attribute__((address_space(1))) void*)g,
        (__attribute__((address_space(3))) void*)l, 16, 0, 0);
}

// ---------------- transpose + prep (fused launch, z selects role) ----------------
// z==0/1: [b][f][t] f32 -> Xt[b][t][k] bf16 (k = z*NFREQ + f)
// z==2  : Kc'[c'][k] = RK[512+c'][k]/1024 (k<512), +IK[512+c'][k-512]/1024
//         (512 rows; sign NOT folded — epilogue forms U-V and U+V)
__global__ __launch_bounds__(256) void transpose_prep(const float* __restrict__ magn,
                                                      const float* __restrict__ phase,
                                                      const float* __restrict__ rk,
                                                      const float* __restrict__ ik,
                                                      bf16* __restrict__ Xt,
                                                      bf16* __restrict__ Kc) {
    const int tid = threadIdx.x;
    const int src = blockIdx.z;

    if (src == 2) {                      // prep: 512*1024 elems, guard the tail
        int idx = (blockIdx.y * 512 + blockIdx.x) * 256 + tid;
        if (idx >= 512 * KDIM) return;
        int cp = idx >> 10;              // c' = 0..511, actual row = 512+c'
        int k = idx & 1023;
        int row = 512 + cp;
        float v = (k < NFREQ) ? rk[row * NFREQ + k] : ik[row * NFREQ + (k - NFREQ)];
        Kc[idx] = (bf16)(v * (1.0f / 1024.0f));
        return;
    }

    __shared__ bf16 tile[64][68];
    const int tt  = blockIdx.x & 63;
    const int ft  = blockIdx.x >> 6;
    const int b   = blockIdx.y;
    const float* in = src ? phase : magn;
    const int f0 = ft * 64, t0 = tt * 64;
    const size_t base = (size_t)b * NFREQ * TDIM;

    const int r0 = tid >> 4;
    const int c4 = (tid & 15) * 4;
#pragma unroll
    for (int i = 0; i < 4; i++) {
        int r = r0 + i * 16;
        const float4 v = *(const float4*)&in[base + (size_t)(f0 + r) * TDIM + t0 + c4];
        tile[r][c4 + 0] = (bf16)v.x;
        tile[r][c4 + 1] = (bf16)v.y;
        tile[r][c4 + 2] = (bf16)v.z;
        tile[r][c4 + 3] = (bf16)v.w;
    }
    __syncthreads();
    const int kbase = src * NFREQ + f0;
#pragma unroll
    for (int i = 0; i < 2; i++) {
        int ch = tid + 256 * i;
        int tr = ch >> 3;
        int c8 = (ch & 7) * 8;
        bf16x8 o;
#pragma unroll
        for (int j = 0; j < 8; j++) o[j] = tile[c8 + j][tr];
        *(bf16x8*)&Xt[((size_t)b * TDIM + t0 + tr) * KDIM + kbase + c8] = o;
    }
}

// ---------------- GEMM with DFT symmetry: half the MFMA work ----------------
// U[c'] = K-tiles 0..7  (RK rows 512+c' vs m),  V[c'] = K-tiles 8..15 (IK vs p).
// out[512+mrow] = U - V ;  out[512-mrow] = U + V (mrow>0) ; row 0 via x>=64 blocks.
// Tile 256x128, BK=64, 8-wave, R4-verified schedule per tile; acc split U/V by
// loop (compile-static, rule #20). One tile per WG (persistence BANNED, R3/R9).
// Decode: bm=x>>5 (0..1), bn=x&31 (t tiles of 128); gid%8 = x%8 (80%8==0... grid
// x=80: gid%8=(y*80+x)%8=x%8) -> both bm-sharers of a (b,bn) panel on one XCD.
__global__ __launch_bounds__(512, 2) void gemm8(const bf16* __restrict__ Kc,
                                                const bf16* __restrict__ Xt,
                                                float* __restrict__ out) {
    extern __shared__ __align__(16) char smem[];

    const int tid = threadIdx.x;
    const int w = tid >> 6;          // wave 0..7
    const int l = tid & 63;
    const int x = blockIdx.x;
    const int b = blockIdx.y;

    // ---- row-0 duty blocks: out[b][0][t] = sum_k w_k * Xt[b][t][k<512] / 1024
    if (x >= 64) {
        const int bn0 = x - 64;              // 0..15, t-range bn0*256
        for (int i = 0; i < 32; ++i) {
            const int t = bn0 * 256 + w * 32 + i;
            const bf16x8 v = *(const bf16x8*)&Xt[((size_t)b * TDIM + t) * KDIM + l * 8];
            float s = 0.f;
#pragma unroll
            for (int j = 0; j < 8; j++) s += (float)v[j];
            if (l == 63) s -= 0.5f * (float)v[7];    // freq 512 weight 1 (not 2)
            s *= 2.0f;
#pragma unroll
            for (int m_ = 32; m_ >= 1; m_ >>= 1) s += __shfl_xor(s, m_);
            if (l == 0) out[(size_t)b * CDIM * TDIM + t] = s * (1.0f / 1024.0f);
        }
        return;
    }

    const int bm = x >> 5;           // 0..1  (c' tiles of 256)
    const int bn = x & 31;           // 0..31 (t tiles of 128)

    const bf16* Ab    = Kc + (size_t)(bm * 256) * KDIM;
    const bf16* Bbase = Xt + ((size_t)b * TDIM + bn * 128) * KDIM;

    // staging geometry (R4-verified pattern; B mirrors it at 64 rows/step)
    const int srow  = ((w >> 2) * 128) + ((w & 3) * 8);
    const int srowB = ((w >> 2) * 64) + ((w & 3) * 8);
    const int ssub  = l >> 3;
    const int scol  = ((l & 7) ^ ssub) * 8;

    // fragment-read geometry
    const int wr = w >> 2;           // 0..1 (M half)
    const int wc = w & 3;            // 0..3 (N quarter of 128 -> 32 each)
    const int fr = l & 15;
    const int l16 = l >> 4;
    const int fx = fr & 7;

    f32x4 accU[8][2] = {};
    f32x4 accV[8][2] = {};

#define STAGE_A(curb, q, kt) \
    gload_lds16(Ab + (size_t)(srow + (q)*32 + ssub) * KDIM + (kt)*64 + scol, \
                smem + (curb)*BUFSZ + (srow + (q)*32) * 128)
#define STAGE_B(curb, q, kt) \
    gload_lds16(Bbase + (size_t)(srowB + (q)*32 + ssub) * KDIM + (kt)*64 + scol, \
                smem + (curb)*BUFSZ + ABYTES + (srowB + (q)*32) * 128)

    // prologue: tile0 A(4)+B(2) into buf0; tile1 A q0..2 into buf1; keep 3
#pragma unroll
    for (int q = 0; q < 4; q++) STAGE_A(0, q, 0);
    STAGE_B(0, 0, 0); STAGE_B(0, 1, 0);
    STAGE_A(1, 0, 1); STAGE_A(1, 1, 1); STAGE_A(1, 2, 1);
    asm volatile("s_waitcnt vmcnt(3)" ::: "memory");
    __builtin_amdgcn_s_barrier();
    __builtin_amdgcn_sched_barrier(0);

    // per-tile body: schedule byte-equivalent to R4/R11; ACC selects U or V
#define GTILE(ACC, v)                                                          \
    {                                                                          \
        const int cur = (v) & 1;                                               \
        const char* At = smem + cur * BUFSZ;                                   \
        const char* Bt = At + ABYTES;                                          \
        bf16x8 bfr[2][2];                                                      \
        _Pragma("unroll")                                                      \
        for (int p = 0; p < 4; p++) {                                          \
            bf16x8 afr[2][2];                                                  \
            _Pragma("unroll")                                                  \
            for (int mi = 0; mi < 2; mi++)                                     \
                _Pragma("unroll")                                              \
                for (int kk = 0; kk < 2; kk++) {                               \
                    const int r = wr * 128 + (p * 2 + mi) * 16 + fr;           \
                    afr[mi][kk] = *(const bf16x8*)(At + r * 128                \
                                   + (((kk * 4 + l16) ^ fx) * 16));            \
                }                                                              \
            if (p == 0) {                                                      \
                _Pragma("unroll")                                              \
                for (int n = 0; n < 2; n++)                                    \
                    _Pragma("unroll")                                          \
                    for (int kk = 0; kk < 2; kk++) {                           \
                        const int r = wc * 32 + n * 16 + fr;                   \
                        bfr[n][kk] = *(const bf16x8*)(Bt + r * 128             \
                                      + (((kk * 4 + l16) ^ fx) * 16));         \
                    }                                                          \
            }                                                                  \
            if (p == 0) {                                                      \
                if ((v) + 1 < NT) {                                            \
                    const int nc = cur ^ 1;                                    \
                    STAGE_A(nc, 3, (v) + 1);                                   \
                    STAGE_B(nc, 0, (v) + 1); STAGE_B(nc, 1, (v) + 1);          \
                }                                                              \
            } else {                                                           \
                if ((v) + 2 < NT) STAGE_A(cur, p - 1, (v) + 2);                \
            }                                                                  \
            __builtin_amdgcn_s_barrier();                                      \
            __builtin_amdgcn_s_setprio(1);                                     \
            _Pragma("unroll")                                                  \
            for (int mi = 0; mi < 2; mi++)                                     \
                _Pragma("unroll")                                              \
                for (int n = 0; n < 2; n++)                                    \
                    _Pragma("unroll")                                          \
                    for (int kk = 0; kk < 2; kk++)                             \
                        ACC[p * 2 + mi][n] = __builtin_amdgcn_mfma_f32_16x16x32_bf16( \
                            afr[mi][kk], bfr[n][kk], ACC[p * 2 + mi][n], 0, 0, 0);    \
            __builtin_amdgcn_s_setprio(0);                                     \
            if (p == 3) {                                                      \
                if ((v) < NT - 2) { asm volatile("s_waitcnt vmcnt(3)" ::: "memory"); } \
                else              { asm volatile("s_waitcnt vmcnt(0)" ::: "memory"); } \
            }                                                                  \
            __builtin_amdgcn_s_barrier();                                      \
            __builtin_amdgcn_sched_barrier(0);                                 \
        }                                                                      \
    }

    for (int v = 0; v < 8; ++v)  GTILE(accU, v)      // U: RK vs m (k 0..511)
    for (int v = 8; v < 15; ++v) GTILE(accV, v)      // V: IK vs p (k 512..959)

    // -------- peeled final tile (v=15, buf1, accV): barrier-free, fused C-write
    {
        const char* At = smem + BUFSZ;
        const char* Bt = At + ABYTES;
        const int cr = l16 * 4;
        const int cc = fr;
        // columns: bn*128 + wc*32 + n*16 + cc
        const size_t obatch = (size_t)b * CDIM * TDIM;
        const int colbase = bn * 128 + wc * 32;
        bf16x8 bfr[2][2];

#pragma unroll
        for (int p = 0; p < 4; p++) {
            bf16x8 afr[2][2];
#pragma unroll
            for (int mi = 0; mi < 2; mi++)
#pragma unroll
                for (int kk = 0; kk < 2; kk++) {
                    const int r = wr * 128 + (p * 2 + mi) * 16 + fr;
                    afr[mi][kk] = *(const bf16x8*)(At + r * 128 + (((kk * 4 + l16) ^ fx) * 16));
                }
            if (p == 0) {
#pragma unroll
                for (int n = 0; n < 2; n++)
#pragma unroll
                    for (int kk = 0; kk < 2; kk++) {
                        const int r = wc * 32 + n * 16 + fr;
                        bfr[n][kk] = *(const bf16x8*)(Bt + r * 128 + (((kk * 4 + l16) ^ fx) * 16));
                    }
            }

            __builtin_amdgcn_s_setprio(1);
#pragma unroll
            for (int mi = 0; mi < 2; mi++)
#pragma unroll
                for (int n = 0; n < 2; n++)
#pragma unroll
                    for (int kk = 0; kk < 2; kk++)
                        accV[p * 2 + mi][n] = __builtin_amdgcn_mfma_f32_16x16x32_bf16(
                            afr[mi][kk], bfr[n][kk], accV[p * 2 + mi][n], 0, 0, 0);
            __builtin_amdgcn_s_setprio(0);

            // quarters m = 2p, 2p+1 final -> paired stores drain under p+1
#pragma unroll
            for (int mi = 0; mi < 2; mi++) {
                const int m = p * 2 + mi;
#pragma unroll
                for (int n = 0; n < 2; n++)
#pragma unroll
                    for (int j = 0; j < 4; j++) {
                        const int mrow = bm * 256 + wr * 128 + m * 16 + cr + j;
                        const float u = accU[m][n][j];
                        const float vv = accV[m][n][j];
                        const int col = colbase + n * 16 + cc;
                        if (mrow > 0)
                            out[obatch + (size_t)(512 - mrow) * TDIM + col] = u + vv;
                        out[obatch + (size_t)(512 + mrow) * TDIM + col] = u - vv;
                    }
            }
        }
    }
#undef GTILE
#undef STAGE_A
#undef STAGE_B
}

// ---------------- fallback (ws too small): naive f32 ----------------
__global__ __launch_bounds__(256) void naive_kernel(const float* __restrict__ m,
                                                    const float* __restrict__ p,
                                                    const float* __restrict__ rk,
                                                    const float* __restrict__ ik,
                                                    float* __restrict__ out) {
    size_t idx = (size_t)blockIdx.x * 256 + threadIdx.x;
    int t = idx & 4095;
    size_t r = idx >> 12;
    int c = (int)(r & 1023);
    int b = (int)(r >> 10);
    float acc = 0.f;
    for (int f = 0; f < NFREQ; f++) {
        acc += rk[c * NFREQ + f] * m[((size_t)b * NFREQ + f) * TDIM + t]
             - ik[c * NFREQ + f] * p[((size_t)b * NFREQ + f) * TDIM + t];
    }
    out[idx] = acc * (1.0f / 1024.0f);
}

extern "C" void kernel_launch(void* const* d_in, const int* in_sizes, int n_in,
                              void* d_out, int out_size, void* d_ws, size_t ws_size,
                              hipStream_t stream) {
    const float* magn  = (const float*)d_in[0];
    const float* phase = (const float*)d_in[1];
    const float* rk    = (const float*)d_in[2];
    const float* ik    = (const float*)d_in[3];
    float* out = (float*)d_out;

    const size_t kc_bytes = (size_t)512 * KDIM * sizeof(bf16);           // 1 MB
    const size_t xt_bytes = (size_t)BATCH * TDIM * KDIM * sizeof(bf16);  // 64 MB
    if (ws_size < kc_bytes + xt_bytes) {
        naive_kernel<<<(CDIM * TDIM * BATCH) / 256, 256, 0, stream>>>(magn, phase, rk, ik, out);
        return;
    }

    bf16* Kc = (bf16*)d_ws;
    bf16* Xt = (bf16*)((char*)d_ws + kc_bytes);

    (void)hipFuncSetAttribute((const void*)gemm8,
                              hipFuncAttributeMaxDynamicSharedMemorySize, LDS_TOTAL);

    transpose_prep<<<dim3(512, BATCH, 3), 256, 0, stream>>>(magn, phase, rk, ik, Xt, Kc);
    gemm8<<<dim3(80, BATCH), 512, LDS_TOTAL, stream>>>(Kc, Xt, out);
}